// Round 16
// baseline (65.484 us; speedup 1.0000x reference)
//
#include <hip/hip_runtime.h>
#include <hip/hip_bf16.h>

#define HW 3136
#define W56 56

typedef __attribute__((ext_vector_type(8))) short short8;
typedef __attribute__((ext_vector_type(4))) float f32x4;

static __device__ __forceinline__ f32x4 mfma16(short8 a, short8 b, f32x4 c) {
    return __builtin_amdgcn_mfma_f32_16x16x32_bf16(a, b, c, 0, 0, 0);
}
static __device__ __forceinline__ float b2f(unsigned short u) {
    unsigned int x = ((unsigned int)u) << 16;
    return __builtin_bit_cast(float, x);
}
static __device__ __forceinline__ unsigned short f2b(float f) {
    __hip_bfloat16 h = __float2bfloat16(f);
    return *(unsigned short*)&h;
}

// ---------------- prep ----------------
// blocks 0..3135: transpose x -> catb bf16 cols 0..255 (hi) + xlo bf16 [4HW][256]
// blocks 3136..3647: weight conversion (Wqk split hi/lo, Wv plain bf16)
__global__ __launch_bounds__(256) void prep(const float* __restrict__ x,
                                            const float* __restrict__ Wq, const float* __restrict__ Wk,
                                            const float* __restrict__ Wv,
                                            unsigned short* __restrict__ catb,
                                            unsigned short* __restrict__ xlo,
                                            unsigned short* __restrict__ Wqk_hi,
                                            unsigned short* __restrict__ Wqk_lo,
                                            unsigned short* __restrict__ Wvb) {
    __shared__ float tile[32][33];
    int bx = blockIdx.x, tid = threadIdx.x;
    if (bx < 3136) {
        int b = bx / 784, rem = bx % 784;
        int p0 = (rem >> 3) * 32, c0 = (rem & 7) * 32;
        int tx = tid & 31, ty = tid >> 5;
#pragma unroll
        for (int i = ty; i < 32; i += 8)
            tile[i][tx] = x[((size_t)b * 256 + c0 + i) * HW + p0 + tx];
        __syncthreads();
        // phase 2: pxl = pixel-local (0..31), cg = channel-group of 4 (0..7)
        int pxl = tid >> 3, cg = tid & 7;
        ushort4 h4, l4;
#pragma unroll
        for (int u = 0; u < 4; ++u) {
            float v = tile[cg * 4 + u][pxl];
            unsigned short hi = f2b(v);
            ((unsigned short*)&h4)[u] = hi;
            ((unsigned short*)&l4)[u] = f2b(v - b2f(hi));
        }
        size_t row = (size_t)b * HW + p0 + pxl;
        *(ushort4*)&catb[row * 512 + c0 + cg * 4] = h4;
        *(ushort4*)&xlo[row * 256 + c0 + cg * 4] = l4;
    } else {
        int i = (bx - 3136) * 256 + tid;
        if (i < 32768) {
            float w = (i < 16384) ? Wq[i] : Wk[i - 16384];
            unsigned short hi = f2b(w);
            Wqk_hi[i] = hi;
            Wqk_lo[i] = f2b(w - b2f(hi));
        }
        if (i < 131072) Wvb[i] = f2b(Wv[i]);
    }
}

// ---------------- projqk: 64 W-rows x px(32), K=256, split-bf16, software-pipelined ----------------
// grid.x = npx/32, grid.y = 2 (y=0 -> Q rows 0..63 f32 out; y=1 -> K rows 64..127 bf16 out).
__global__ __launch_bounds__(256) void projqk(const unsigned short* __restrict__ Whi,
                                              const unsigned short* __restrict__ Wlo,
                                              const unsigned short* __restrict__ Bhi_g, int bstr,
                                              const unsigned short* __restrict__ Blo_g,
                                              float* __restrict__ Qout,
                                              unsigned short* __restrict__ Kout) {
    __shared__ short Ahi[64][72], Alo[64][72];
    __shared__ short Bhi[32][72], Blo[32][72];
    int tid = threadIdx.x, lane = tid & 63, wv = tid >> 6;
    int l15 = lane & 15, lk = (lane >> 4) * 8;
    int pxb = blockIdx.x * 32;
    int y64 = blockIdx.y * 64;
    int ar0 = tid >> 3, ac = (tid & 7) * 8;
    int br = tid >> 3, bc = (tid & 7) * 8;
    f32x4 acc[2];
    acc[0] = (f32x4){0.f, 0.f, 0.f, 0.f};
    acc[1] = (f32x4){0.f, 0.f, 0.f, 0.f};

    short8 rAh0 = *(const short8*)(Whi + (size_t)(y64 + ar0) * 256 + ac);
    short8 rAl0 = *(const short8*)(Wlo + (size_t)(y64 + ar0) * 256 + ac);
    short8 rAh1 = *(const short8*)(Whi + (size_t)(y64 + ar0 + 32) * 256 + ac);
    short8 rAl1 = *(const short8*)(Wlo + (size_t)(y64 + ar0 + 32) * 256 + ac);
    short8 rBh  = *(const short8*)(Bhi_g + (size_t)(pxb + br) * bstr + bc);
    short8 rBl  = *(const short8*)(Blo_g + (size_t)(pxb + br) * 256 + bc);

#pragma unroll
    for (int t = 0; t < 4; ++t) {
        *(short8*)&Ahi[ar0][ac] = rAh0;      *(short8*)&Alo[ar0][ac] = rAl0;
        *(short8*)&Ahi[ar0 + 32][ac] = rAh1; *(short8*)&Alo[ar0 + 32][ac] = rAl1;
        *(short8*)&Bhi[br][bc] = rBh;        *(short8*)&Blo[br][bc] = rBl;
        __syncthreads();
        if (t < 3) {
            int kn = t * 64 + 64;
            rAh0 = *(const short8*)(Whi + (size_t)(y64 + ar0) * 256 + kn + ac);
            rAl0 = *(const short8*)(Wlo + (size_t)(y64 + ar0) * 256 + kn + ac);
            rAh1 = *(const short8*)(Whi + (size_t)(y64 + ar0 + 32) * 256 + kn + ac);
            rAl1 = *(const short8*)(Wlo + (size_t)(y64 + ar0 + 32) * 256 + kn + ac);
            rBh  = *(const short8*)(Bhi_g + (size_t)(pxb + br) * bstr + kn + bc);
            rBl  = *(const short8*)(Blo_g + (size_t)(pxb + br) * 256 + kn + bc);
        }
#pragma unroll
        for (int ks = 0; ks < 2; ++ks) {
            short8 ah = *(const short8*)&Ahi[wv * 16 + l15][ks * 32 + lk];
            short8 al = *(const short8*)&Alo[wv * 16 + l15][ks * 32 + lk];
            short8 bh[2], bl[2];
#pragma unroll
            for (int j = 0; j < 2; ++j) {
                bh[j] = *(const short8*)&Bhi[j * 16 + l15][ks * 32 + lk];
                bl[j] = *(const short8*)&Blo[j * 16 + l15][ks * 32 + lk];
            }
#pragma unroll
            for (int j = 0; j < 2; ++j) {
                acc[j] = mfma16(ah, bh[j], acc[j]);
                acc[j] = mfma16(ah, bl[j], acc[j]);
                acc[j] = mfma16(al, bh[j], acc[j]);
            }
        }
        __syncthreads();
    }
    int d0 = wv * 16 + (lane >> 4) * 4;
    if (blockIdx.y == 0) {
#pragma unroll
        for (int j = 0; j < 2; ++j) {
            int px = pxb + j * 16 + l15;
            *(f32x4*)(Qout + (size_t)px * 64 + d0) = acc[j];
        }
    } else {
#pragma unroll
        for (int j = 0; j < 2; ++j) {
            int px = pxb + j * 16 + l15;
            ushort4 kb;
            kb.x = f2b(acc[j][0]); kb.y = f2b(acc[j][1]);
            kb.z = f2b(acc[j][2]); kb.w = f2b(acc[j][3]);
            *(ushort4*)(Kout + (size_t)px * 64 + d0) = kb;
        }
    }
}

// ---------------- attn body (device fn): one wave per pixel, barrier-free, bf16 K ----------------
// lb must be the XCD-swizzled logical block id in [0, 1568). smem: >=2048B scratch.
static __device__ __forceinline__ void attn_body(int lb, int tid, char* smem,
                                                 const float* __restrict__ Q,
                                                 const unsigned short* __restrict__ Kb,
                                                 int selfOff, int kbOff,
                                                 const unsigned short* __restrict__ V,
                                                 unsigned short* __restrict__ outb,
                                                 unsigned short* __restrict__ outlo) {
    float* wsh = (float*)smem;        // [4][64]
    int* njsh = (int*)(smem + 1024);  // [4][64]
    int lane = tid & 63, wv = tid >> 6;
    int gw = lb * 4 + wv;
    int b = gw / HW, pix = gw % HW;
    int py = pix / W56, px = pix % W56;

    int valid = 0, nj = 0;
    if (lane == 0) {
        valid = 1;
    } else if (lane < 50) {
        int d = lane - 1, dy = d / 7 - 3, dx = d % 7 - 3;
        int ny = py + dy, nx = px + dx;
        if (ny >= 0 && ny < W56 && nx >= 0 && nx < W56) { valid = 1; nj = ny * W56 + nx; }
    }
    njsh[wv * 64 + lane] = nj;  // per-wave LDS; read below by same wave only

    // ---- K gathers (7 x short8 = 16B/lane, coalesced-transposed, bf16 rows) ----
    int rg = lane >> 3, c8 = lane & 7;
    f32x4 qf0 = *(const f32x4*)(Q + (size_t)gw * 64 + c8 * 8);
    f32x4 qf1 = *(const f32x4*)(Q + (size_t)gw * 64 + c8 * 8 + 4);
    short8 kvv[7];
#pragma unroll
    for (int i = 0; i < 7; ++i) {
        int j = i * 8 + rg;
        int row = (i == 0 && rg == 0) ? (selfOff + gw) : (kbOff + b * HW + njsh[wv * 64 + j]);
        kvv[i] = *(const short8*)(Kb + (size_t)row * 64 + c8 * 8);
    }

    __builtin_amdgcn_s_setprio(1);

    // ---- logits: per-lane chunk-pair partial + 3-step butterfly over the 8 c8 lanes ----
    float pl[7];
#pragma unroll
    for (int i = 0; i < 7; ++i) {
        float pA = b2f((unsigned short)kvv[i][0]) * qf0[0] + b2f((unsigned short)kvv[i][1]) * qf0[1] +
                   b2f((unsigned short)kvv[i][2]) * qf0[2] + b2f((unsigned short)kvv[i][3]) * qf0[3];
        float pB = b2f((unsigned short)kvv[i][4]) * qf1[0] + b2f((unsigned short)kvv[i][5]) * qf1[1] +
                   b2f((unsigned short)kvv[i][6]) * qf1[2] + b2f((unsigned short)kvv[i][7]) * qf1[3];
        pl[i] = pA + pB;
    }
#pragma unroll
    for (int off = 1; off < 8; off <<= 1)
#pragma unroll
        for (int i = 0; i < 7; ++i) pl[i] += __shfl_xor(pl[i], off);
    // lane (rg,c8) holds row c8*8+rg's logit; lane j wants row j -> bit-swap shfl
    float myl = 0.f;
#pragma unroll
    for (int i = 0; i < 7; ++i) myl = (c8 == i) ? pl[i] : myl;
    float tl = __shfl(myl, ((lane & 7) << 3) | (lane >> 3));

    // ---- softmax (zero-padded OOB neighbors: logit exactly 0, in denominator) ----
    float logit = (lane < 50 && valid) ? tl : 0.f;
    float m = (lane < 50) ? logit : -1e30f;
#pragma unroll
    for (int off = 32; off; off >>= 1) m = fmaxf(m, __shfl_xor(m, off));
    float e = (lane < 50) ? __expf(logit - m) : 0.f;
    float s = e;
#pragma unroll
    for (int off = 32; off; off >>= 1) s += __shfl_xor(s, off);
    float w = (lane >= 1 && lane < 50 && valid) ? e / s : 0.f;
    wsh[wv * 64 + lane] = w;

    // ---- PV: half-row split, 8 channels/lane, 12 loads in flight ----
    int h = lane >> 5, l32 = lane & 31;
    int jb = h * 25;  // h=0: rows 0..24, h=1: rows 25..49 (row 0 has w=0)
    float av[8];
#pragma unroll
    for (int cc = 0; cc < 8; ++cc) av[cc] = 0.f;
    const unsigned short* vb = V + (size_t)b * HW * 512 + l32 * 8;
#pragma unroll
    for (int g = 0; g < 2; ++g) {
        float wj[12];
        short8 vj[12];
#pragma unroll
        for (int u = 0; u < 12; ++u) {
            int j = jb + g * 12 + u;
            wj[u] = wsh[wv * 64 + j];
            vj[u] = *(const short8*)(vb + (size_t)njsh[wv * 64 + j] * 512);
        }
#pragma unroll
        for (int u = 0; u < 12; ++u)
#pragma unroll
            for (int cc = 0; cc < 8; ++cc)
                av[cc] += wj[u] * b2f((unsigned short)vj[u][cc]);
    }
    {   // tail row j = jb + 24
        int j = jb + 24;
        float wt = wsh[wv * 64 + j];
        short8 vt = *(const short8*)(vb + (size_t)njsh[wv * 64 + j] * 512);
#pragma unroll
        for (int cc = 0; cc < 8; ++cc) av[cc] += wt * b2f((unsigned short)vt[cc]);
    }
#pragma unroll
    for (int cc = 0; cc < 8; ++cc) av[cc] += __shfl_xor(av[cc], 32);

    __builtin_amdgcn_s_setprio(0);

    if (h == 0) {
        short8 pk, lo8;
#pragma unroll
        for (int cc = 0; cc < 8; ++cc) {
            unsigned short hi = f2b(av[cc]);
            pk[cc] = (short)hi;
            lo8[cc] = (short)f2b(av[cc] - b2f(hi));
        }
        *(short8*)(outb + (size_t)gw * 512 + l32 * 8) = pk;
        if (outlo) *(short8*)(outlo + (size_t)gw * 256 + l32 * 8) = lo8;
    }
}

// ---------------- conv body (device fn): 64x64 tile of the 512->256 GEMM + BN + ReLU ----------------
static __device__ __forceinline__ void conv_body(int n0g, int m0g, int tid, char* smem,
                                                 const unsigned short* __restrict__ catb,
                                                 const unsigned short* __restrict__ Wvb,
                                                 const float* __restrict__ bv, const float* __restrict__ gamma,
                                                 const float* __restrict__ beta, const float* __restrict__ rmean,
                                                 const float* __restrict__ rvar, float* __restrict__ out) {
    short(*Ald)[72] = (short(*)[72])smem;
    short(*Bld)[72] = (short(*)[72])(smem + 64 * 72 * 2);
    int lane = tid & 63, wv = tid >> 6;
    int wm = wv >> 1, wn = wv & 1;
    int l15 = lane & 15, lk = (lane >> 4) * 8;
    f32x4 acc[2][2];
#pragma unroll
    for (int i = 0; i < 2; ++i)
#pragma unroll
        for (int j = 0; j < 2; ++j) acc[i][j] = (f32x4){0.f, 0.f, 0.f, 0.f};

    float sc_[2][4], sh_[2][4];
#pragma unroll
    for (int i = 0; i < 2; ++i) {
        int ob = m0g + wm * 32 + i * 16 + (lane >> 4) * 4;
#pragma unroll
        for (int r = 0; r < 4; ++r) {
            int o = ob + r;
            float s = gamma[o] * rsqrtf(rvar[o] + 1e-5f);
            sc_[i][r] = s;
            sh_[i][r] = (bv[o] - rmean[o]) * s + beta[o];
        }
    }

    for (int kt = 0; kt < 512; kt += 64) {
#pragma unroll
        for (int s = 0; s < 2; ++s) {
            int q = tid + 256 * s;
            int r = q >> 3, c = (q & 7) * 8;
            *(short8*)&Ald[r][c] = *(const short8*)(Wvb + (size_t)(m0g + r) * 512 + kt + c);
            *(short8*)&Bld[r][c] = *(const short8*)(catb + (size_t)(n0g + r) * 512 + kt + c);
        }
        __syncthreads();
#pragma unroll
        for (int ks = 0; ks < 2; ++ks) {
            short8 a[2], b[2];
#pragma unroll
            for (int i = 0; i < 2; ++i) a[i] = *(const short8*)&Ald[wm * 32 + i * 16 + l15][ks * 32 + lk];
#pragma unroll
            for (int j = 0; j < 2; ++j) b[j] = *(const short8*)&Bld[wn * 32 + j * 16 + l15][ks * 32 + lk];
#pragma unroll
            for (int i = 0; i < 2; ++i)
#pragma unroll
                for (int j = 0; j < 2; ++j) acc[i][j] = mfma16(a[i], b[j], acc[i][j]);
        }
        __syncthreads();
    }
#pragma unroll
    for (int i = 0; i < 2; ++i) {
        int ob = m0g + wm * 32 + i * 16 + (lane >> 4) * 4;
#pragma unroll
        for (int j = 0; j < 2; ++j) {
            int px = n0g + wn * 32 + j * 16 + l15;
            int b = px / HW, p = px - b * HW;
            f32x4 v = acc[i][j];
#pragma unroll
            for (int r = 0; r < 4; ++r) {
                out[((size_t)(b * 256 + ob + r)) * HW + p] = fmaxf(v[r] * sc_[i][r] + sh_[i][r], 0.f);
            }
        }
    }
}

// ---------------- standalone attn (attn1) ----------------
__global__ __launch_bounds__(256) void attn_kernel(const float* __restrict__ Q,
                                                   const unsigned short* __restrict__ Kb,
                                                   int selfOff, int kbOff,
                                                   const unsigned short* __restrict__ V,
                                                   unsigned short* __restrict__ outb,
                                                   unsigned short* __restrict__ outlo) {
    __shared__ __align__(16) char smem[2048];
    int bx = blockIdx.x;
    int lb = (bx & 7) * 196 + (bx >> 3);  // XCD swizzle over 1568 blocks
    attn_body(lb, threadIdx.x, smem, Q, Kb, selfOff, kbOff, V, outb, outlo);
}

// ---------------- merged attn2 + conv(batches 0,1): independent work, one launch ----------------
// blocks 0..1567: attn2 (XCD-swizzled). blocks 1568..1959: conv tiles over pixels 0..6271
// (catb batches 0,1: x from prep, xt1 from attn1 -- no dependency on attn2's output).
// conv01's MFMA work hides under attn2's VMEM-issue-bound execution.
__global__ __launch_bounds__(256) void attn2_conv01(const float* __restrict__ Q,
                                                    const unsigned short* __restrict__ Kb,
                                                    int selfOff, int kbOff,
                                                    const unsigned short* __restrict__ V,
                                                    unsigned short* __restrict__ outb,
                                                    const unsigned short* __restrict__ catb,
                                                    const unsigned short* __restrict__ Wvb,
                                                    const float* __restrict__ bv, const float* __restrict__ gamma,
                                                    const float* __restrict__ beta, const float* __restrict__ rmean,
                                                    const float* __restrict__ rvar, float* __restrict__ out) {
    __shared__ __align__(16) char smem[2 * 64 * 72 * 2];  // union: conv tiles (18432B) / attn tables (2048B)
    int bx = blockIdx.x;
    if (bx < 1568) {
        int lb = (bx & 7) * 196 + (bx >> 3);
        attn_body(lb, threadIdx.x, smem, Q, Kb, selfOff, kbOff, V, outb, nullptr);
    } else {
        int cb = bx - 1568;                 // 0..391
        int n0g = (cb >> 2) * 64;           // pixels 0..6271 (batches 0,1)
        int m0g = (cb & 3) * 64;
        conv_body(n0g, m0g, threadIdx.x, smem, catb, Wvb, bv, gamma, beta, rmean, rvar, out);
    }
}

// ---------------- standalone conv (batches 2,3) ----------------
__global__ __launch_bounds__(256) void conv_mfma(const unsigned short* __restrict__ catb,
                                                 const unsigned short* __restrict__ Wvb,
                                                 const float* __restrict__ bv, const float* __restrict__ gamma,
                                                 const float* __restrict__ beta, const float* __restrict__ rmean,
                                                 const float* __restrict__ rvar, float* __restrict__ out,
                                                 int n_base) {
    __shared__ __align__(16) char smem[2 * 64 * 72 * 2];
    int n0g = n_base + blockIdx.x * 64;
    int m0g = blockIdx.y * 64;
    conv_body(n0g, m0g, threadIdx.x, smem, catb, Wvb, bv, gamma, beta, rmean, rvar, out);
}

extern "C" void kernel_launch(void* const* d_in, const int* in_sizes, int n_in,
                              void* d_out, int out_size, void* d_ws, size_t ws_size,
                              hipStream_t stream) {
    const float* x     = (const float*)d_in[0];
    const float* Wq    = (const float*)d_in[1];
    const float* Wk    = (const float*)d_in[2];
    const float* Wv    = (const float*)d_in[3];
    const float* bv    = (const float*)d_in[4];
    const float* gamma = (const float*)d_in[5];
    const float* beta  = (const float*)d_in[6];
    const float* rmean = (const float*)d_in[7];
    const float* rvar  = (const float*)d_in[8];
    float* out = (float*)d_out;

    float* Qall = (float*)d_ws;                              // [4*HW][64] f32
    float* Qn   = Qall + (size_t)4 * HW * 64;                // [2*HW][64] f32
    unsigned short* Kb = (unsigned short*)(Qn + (size_t)2 * HW * 64);  // [6*HW][64] bf16
    unsigned short* catb   = Kb + (size_t)6 * HW * 64;       // [4*HW][512]
    unsigned short* xlo    = catb + (size_t)4 * HW * 512;    // [4*HW][256]
    unsigned short* xt1lo  = xlo + (size_t)4 * HW * 256;     // [2*HW][256]
    unsigned short* Wqk_hi = xt1lo + (size_t)2 * HW * 256;   // [128][256]
    unsigned short* Wqk_lo = Wqk_hi + 128 * 256;
    unsigned short* Wvb    = Wqk_lo + 128 * 256;             // [256][512]

    prep<<<3648, 256, 0, stream>>>(x, Wq, Wk, Wv, catb, xlo, Wqk_hi, Wqk_lo, Wvb);

    // Q (f32) and K (bf16, rows 0..4HW) for all 4 batches
    projqk<<<dim3(392, 2), 256, 0, stream>>>(Wqk_hi, Wqk_lo, catb, 512, xlo, Qall, Kb);

    // align 1: ta = x[2:4], tb = x[0:2] -> xt1 (hi -> catb cols 256.., lo -> xt1lo)
    attn_kernel<<<1568, 256, 0, stream>>>(Qall + (size_t)2 * HW * 64, Kb,
                                          /*selfOff=*/2 * HW, /*kbOff=*/0,
                                          catb, catb + 256, xt1lo);

    // Q,K of xt1 (K -> Kb rows 4HW..6HW)
    projqk<<<dim3(196, 2), 256, 0, stream>>>(Wqk_hi, Wqk_lo, catb + 256, 512, xt1lo,
                                             Qn, Kb + (size_t)4 * HW * 64);

    // align 2 (attn2) + conv for batches 0,1 (independent of attn2) in ONE launch
    attn2_conv01<<<1960, 256, 0, stream>>>(Qn, Kb,
                                           /*selfOff=*/4 * HW, /*kbOff=*/2 * HW,
                                           catb + (size_t)2 * HW * 512,
                                           catb + (size_t)2 * HW * 512 + 256,
                                           catb, Wvb, bv, gamma, beta, rmean, rvar, out);

    // conv for batches 2,3 (needs attn2's xt2)
    conv_mfma<<<dim3(98, 4), 256, 0, stream>>>(catb, Wvb, bv, gamma, beta, rmean, rvar, out,
                                               /*n_base=*/98 * 64);
}

// Round 17
// 59.680 us; speedup vs baseline: 1.0972x; 1.0972x over previous
//
#include <hip/hip_runtime.h>
#include <hip/hip_bf16.h>

#define HW 3136
#define W56 56

typedef __attribute__((ext_vector_type(8))) short short8;
typedef __attribute__((ext_vector_type(4))) float f32x4;

static __device__ __forceinline__ f32x4 mfma16(short8 a, short8 b, f32x4 c) {
    return __builtin_amdgcn_mfma_f32_16x16x32_bf16(a, b, c, 0, 0, 0);
}
static __device__ __forceinline__ float b2f(unsigned short u) {
    unsigned int x = ((unsigned int)u) << 16;
    return __builtin_bit_cast(float, x);
}
static __device__ __forceinline__ unsigned short f2b(float f) {
    __hip_bfloat16 h = __float2bfloat16(f);
    return *(unsigned short*)&h;
}

// ---------------- prep ----------------
// blocks 0..3135: transpose x -> catb bf16 cols 0..255 (hi) + xlo bf16 [4HW][256]
// blocks 3136..3647: weight conversion (Wqk split hi/lo, Wv plain bf16)
__global__ __launch_bounds__(256) void prep(const float* __restrict__ x,
                                            const float* __restrict__ Wq, const float* __restrict__ Wk,
                                            const float* __restrict__ Wv,
                                            unsigned short* __restrict__ catb,
                                            unsigned short* __restrict__ xlo,
                                            unsigned short* __restrict__ Wqk_hi,
                                            unsigned short* __restrict__ Wqk_lo,
                                            unsigned short* __restrict__ Wvb) {
    __shared__ float tile[32][33];
    int bx = blockIdx.x, tid = threadIdx.x;
    if (bx < 3136) {
        int b = bx / 784, rem = bx % 784;
        int p0 = (rem >> 3) * 32, c0 = (rem & 7) * 32;
        int tx = tid & 31, ty = tid >> 5;
#pragma unroll
        for (int i = ty; i < 32; i += 8)
            tile[i][tx] = x[((size_t)b * 256 + c0 + i) * HW + p0 + tx];
        __syncthreads();
#pragma unroll
        for (int i = ty; i < 32; i += 8) {
            float v = tile[tx][i];
            unsigned short hi = f2b(v);
            unsigned short lo = f2b(v - b2f(hi));
            size_t row = (size_t)b * HW + p0 + i;
            catb[row * 512 + c0 + tx] = hi;
            xlo[row * 256 + c0 + tx] = lo;
        }
    } else {
        int i = (bx - 3136) * 256 + tid;
        if (i < 32768) {
            float w = (i < 16384) ? Wq[i] : Wk[i - 16384];
            unsigned short hi = f2b(w);
            Wqk_hi[i] = hi;
            Wqk_lo[i] = f2b(w - b2f(hi));
        }
        if (i < 131072) Wvb[i] = f2b(Wv[i]);
    }
}

// ---------------- projqk: 64 W-rows x px(32), K=256, split-bf16, software-pipelined ----------------
// grid.x = npx/32, grid.y = 2 (y=0 -> Q rows 0..63 f32 out; y=1 -> K rows 64..127 bf16 out).
__global__ __launch_bounds__(256) void projqk(const unsigned short* __restrict__ Whi,
                                              const unsigned short* __restrict__ Wlo,
                                              const unsigned short* __restrict__ Bhi_g, int bstr,
                                              const unsigned short* __restrict__ Blo_g,
                                              float* __restrict__ Qout,
                                              unsigned short* __restrict__ Kout) {
    __shared__ short Ahi[64][72], Alo[64][72];
    __shared__ short Bhi[32][72], Blo[32][72];
    int tid = threadIdx.x, lane = tid & 63, wv = tid >> 6;
    int l15 = lane & 15, lk = (lane >> 4) * 8;
    int pxb = blockIdx.x * 32;
    int y64 = blockIdx.y * 64;
    int ar0 = tid >> 3, ac = (tid & 7) * 8;
    int br = tid >> 3, bc = (tid & 7) * 8;
    f32x4 acc[2];
    acc[0] = (f32x4){0.f, 0.f, 0.f, 0.f};
    acc[1] = (f32x4){0.f, 0.f, 0.f, 0.f};

    short8 rAh0 = *(const short8*)(Whi + (size_t)(y64 + ar0) * 256 + ac);
    short8 rAl0 = *(const short8*)(Wlo + (size_t)(y64 + ar0) * 256 + ac);
    short8 rAh1 = *(const short8*)(Whi + (size_t)(y64 + ar0 + 32) * 256 + ac);
    short8 rAl1 = *(const short8*)(Wlo + (size_t)(y64 + ar0 + 32) * 256 + ac);
    short8 rBh  = *(const short8*)(Bhi_g + (size_t)(pxb + br) * bstr + bc);
    short8 rBl  = *(const short8*)(Blo_g + (size_t)(pxb + br) * 256 + bc);

#pragma unroll
    for (int t = 0; t < 4; ++t) {
        *(short8*)&Ahi[ar0][ac] = rAh0;      *(short8*)&Alo[ar0][ac] = rAl0;
        *(short8*)&Ahi[ar0 + 32][ac] = rAh1; *(short8*)&Alo[ar0 + 32][ac] = rAl1;
        *(short8*)&Bhi[br][bc] = rBh;        *(short8*)&Blo[br][bc] = rBl;
        __syncthreads();
        if (t < 3) {
            int kn = t * 64 + 64;
            rAh0 = *(const short8*)(Whi + (size_t)(y64 + ar0) * 256 + kn + ac);
            rAl0 = *(const short8*)(Wlo + (size_t)(y64 + ar0) * 256 + kn + ac);
            rAh1 = *(const short8*)(Whi + (size_t)(y64 + ar0 + 32) * 256 + kn + ac);
            rAl1 = *(const short8*)(Wlo + (size_t)(y64 + ar0 + 32) * 256 + kn + ac);
            rBh  = *(const short8*)(Bhi_g + (size_t)(pxb + br) * bstr + kn + bc);
            rBl  = *(const short8*)(Blo_g + (size_t)(pxb + br) * 256 + kn + bc);
        }
#pragma unroll
        for (int ks = 0; ks < 2; ++ks) {
            short8 ah = *(const short8*)&Ahi[wv * 16 + l15][ks * 32 + lk];
            short8 al = *(const short8*)&Alo[wv * 16 + l15][ks * 32 + lk];
            short8 bh[2], bl[2];
#pragma unroll
            for (int j = 0; j < 2; ++j) {
                bh[j] = *(const short8*)&Bhi[j * 16 + l15][ks * 32 + lk];
                bl[j] = *(const short8*)&Blo[j * 16 + l15][ks * 32 + lk];
            }
#pragma unroll
            for (int j = 0; j < 2; ++j) {
                acc[j] = mfma16(ah, bh[j], acc[j]);
                acc[j] = mfma16(ah, bl[j], acc[j]);
                acc[j] = mfma16(al, bh[j], acc[j]);
            }
        }
        __syncthreads();
    }
    int d0 = wv * 16 + (lane >> 4) * 4;
    if (blockIdx.y == 0) {
#pragma unroll
        for (int j = 0; j < 2; ++j) {
            int px = pxb + j * 16 + l15;
            *(f32x4*)(Qout + (size_t)px * 64 + d0) = acc[j];
        }
    } else {
#pragma unroll
        for (int j = 0; j < 2; ++j) {
            int px = pxb + j * 16 + l15;
            ushort4 kb;
            kb.x = f2b(acc[j][0]); kb.y = f2b(acc[j][1]);
            kb.z = f2b(acc[j][2]); kb.w = f2b(acc[j][3]);
            *(ushort4*)(Kout + (size_t)px * 64 + d0) = kb;
        }
    }
}

// ---------------- attention: one wave per output pixel, barrier-free, bf16 K ----------------
// r13 structure with a 16B/lane K-gather: lane=(rg 0..7, c8 0..7); load i covers rows {8i+rg},
// each lane holds chunks (2c8, 2c8+1) = 8 bf16. K loads 13->7 insts, butterfly 4->3 steps.
// BIT-IDENTICAL logits: pA+pB reproduces the old butterfly's bit-0 pairing (f32 add is
// commutative; the association tree -- pair by bit0, then bits 1,2,3 -- is unchanged).
// Masked row slots j in [50,55] clamp to njsh=0 (real memory; never read downstream).
// PV: half-row split (lanes<32: rows 0..24; >=32: rows 25..49), 8 ch/lane, shfl_xor(32).
__global__ __launch_bounds__(256) void attn_kernel(const float* __restrict__ Q,
                                                   const unsigned short* __restrict__ Kb,
                                                   int selfOff, int kbOff,
                                                   const unsigned short* __restrict__ V,
                                                   unsigned short* __restrict__ outb,
                                                   unsigned short* __restrict__ outlo) {
    __shared__ float wsh[4][64];
    __shared__ float ls[4][56];
    __shared__ int njsh[4][64];
    int tid = threadIdx.x, lane = tid & 63, wv = tid >> 6;
    int nbc = gridDim.x >> 3;  // blocks per XCD chunk (1568/8 = 196)
    int lb = (blockIdx.x & 7) * nbc + (blockIdx.x >> 3);
    int gw = lb * 4 + wv;
    int b = gw / HW, pix = gw % HW;
    int py = pix / W56, px = pix % W56;

    int valid = 0, nj = 0;
    if (lane == 0) {
        valid = 1;
    } else if (lane < 50) {
        int d = lane - 1, dy = d / 7 - 3, dx = d % 7 - 3;
        int ny = py + dy, nx = px + dx;
        if (ny >= 0 && ny < W56 && nx >= 0 && nx < W56) { valid = 1; nj = ny * W56 + nx; }
    }
    njsh[wv][lane] = nj;  // per-wave LDS; read below by same wave only

    // ---- K gathers (7 x short8 = 16B/lane, coalesced-transposed, bf16 rows) ----
    int rg = lane >> 3, c8 = lane & 7;
    f32x4 qf0 = *(const f32x4*)(Q + (size_t)gw * 64 + c8 * 8);
    f32x4 qf1 = *(const f32x4*)(Q + (size_t)gw * 64 + c8 * 8 + 4);
    short8 kvv[7];
#pragma unroll
    for (int i = 0; i < 7; ++i) {
        int j = i * 8 + rg;
        int row = (i == 0 && rg == 0) ? (selfOff + gw) : (kbOff + b * HW + njsh[wv][j]);
        kvv[i] = *(const short8*)(Kb + (size_t)row * 64 + c8 * 8);
    }

    // compute phase: favor this wave's FMA bursts in CU issue arbitration
    __builtin_amdgcn_s_setprio(1);

    // ---- logits: per-lane chunk-pair partial + 3-step butterfly over the 8 c8 lanes ----
    float pl[7];
#pragma unroll
    for (int i = 0; i < 7; ++i) {
        float pA = b2f((unsigned short)kvv[i][0]) * qf0[0] + b2f((unsigned short)kvv[i][1]) * qf0[1] +
                   b2f((unsigned short)kvv[i][2]) * qf0[2] + b2f((unsigned short)kvv[i][3]) * qf0[3];
        float pB = b2f((unsigned short)kvv[i][4]) * qf1[0] + b2f((unsigned short)kvv[i][5]) * qf1[1] +
                   b2f((unsigned short)kvv[i][6]) * qf1[2] + b2f((unsigned short)kvv[i][7]) * qf1[3];
        pl[i] = pA + pB;
    }
#pragma unroll
    for (int off = 1; off < 8; off <<= 1)
#pragma unroll
        for (int i = 0; i < 7; ++i) pl[i] += __shfl_xor(pl[i], off);
    // scatter logits to per-wave LDS: lane (rg,c8) writes row c8*8+rg with pl[c8]
    float myl = 0.f;
#pragma unroll
    for (int i = 0; i < 7; ++i) myl = (c8 == i) ? pl[i] : myl;
    if (c8 < 7) ls[wv][c8 * 8 + rg] = myl;

    // ---- softmax (zero-padded OOB neighbors: logit exactly 0, in denominator) ----
    float logit = (lane < 50 && valid) ? ls[wv][lane] : 0.f;
    float m = (lane < 50) ? logit : -1e30f;
#pragma unroll
    for (int off = 32; off; off >>= 1) m = fmaxf(m, __shfl_xor(m, off));
    float e = (lane < 50) ? __expf(logit - m) : 0.f;
    float s = e;
#pragma unroll
    for (int off = 32; off; off >>= 1) s += __shfl_xor(s, off);
    // self column (lane 0) dropped; OOB & pad lanes weight 0, nj 0 -> branchless V loop exact
    float w = (lane >= 1 && lane < 50 && valid) ? e / s : 0.f;
    wsh[wv][lane] = w;

    // ---- PV: half-row split, 8 channels/lane, 12 loads in flight ----
    int h = lane >> 5, l32 = lane & 31;
    int jb = h * 25;  // h=0: rows 0..24, h=1: rows 25..49 (row 0 has w=0)
    float av[8];
#pragma unroll
    for (int cc = 0; cc < 8; ++cc) av[cc] = 0.f;
    const unsigned short* vb = V + (size_t)b * HW * 512 + l32 * 8;
#pragma unroll
    for (int g = 0; g < 2; ++g) {
        float wj[12];
        short8 vj[12];
#pragma unroll
        for (int u = 0; u < 12; ++u) {
            int j = jb + g * 12 + u;
            wj[u] = wsh[wv][j];
            vj[u] = *(const short8*)(vb + (size_t)njsh[wv][j] * 512);
        }
#pragma unroll
        for (int u = 0; u < 12; ++u)
#pragma unroll
            for (int cc = 0; cc < 8; ++cc)
                av[cc] += wj[u] * b2f((unsigned short)vj[u][cc]);
    }
    {   // tail row j = jb + 24
        int j = jb + 24;
        float wt = wsh[wv][j];
        short8 vt = *(const short8*)(vb + (size_t)njsh[wv][j] * 512);
#pragma unroll
        for (int cc = 0; cc < 8; ++cc) av[cc] += wt * b2f((unsigned short)vt[cc]);
    }
#pragma unroll
    for (int cc = 0; cc < 8; ++cc) av[cc] += __shfl_xor(av[cc], 32);

    __builtin_amdgcn_s_setprio(0);

    if (h == 0) {
        short8 pk, lo8;
#pragma unroll
        for (int cc = 0; cc < 8; ++cc) {
            unsigned short hi = f2b(av[cc]);
            pk[cc] = (short)hi;
            lo8[cc] = (short)f2b(av[cc] - b2f(hi));
        }
        *(short8*)(outb + (size_t)gw * 512 + l32 * 8) = pk;
        if (outlo) *(short8*)(outlo + (size_t)gw * 256 + l32 * 8) = lo8;
    }
}

// ---------------- conv (512->256) via MFMA + BN + ReLU ----------------
__global__ __launch_bounds__(256) void conv_mfma(const unsigned short* __restrict__ catb,
                                                 const unsigned short* __restrict__ Wvb,
                                                 const float* __restrict__ bv, const float* __restrict__ gamma,
                                                 const float* __restrict__ beta, const float* __restrict__ rmean,
                                                 const float* __restrict__ rvar, float* __restrict__ out) {
    __shared__ short Ald[64][72];
    __shared__ short Bld[64][72];
    int tid = threadIdx.x, lane = tid & 63, wv = tid >> 6;
    int wm = wv >> 1, wn = wv & 1;
    int l15 = lane & 15, lk = (lane >> 4) * 8;
    int n0g = blockIdx.x * 64;
    int m0g = blockIdx.y * 64;
    f32x4 acc[2][2];
#pragma unroll
    for (int i = 0; i < 2; ++i)
#pragma unroll
        for (int j = 0; j < 2; ++j) acc[i][j] = (f32x4){0.f, 0.f, 0.f, 0.f};

    float sc_[2][4], sh_[2][4];
#pragma unroll
    for (int i = 0; i < 2; ++i) {
        int ob = m0g + wm * 32 + i * 16 + (lane >> 4) * 4;
#pragma unroll
        for (int r = 0; r < 4; ++r) {
            int o = ob + r;
            float s = gamma[o] * rsqrtf(rvar[o] + 1e-5f);
            sc_[i][r] = s;
            sh_[i][r] = (bv[o] - rmean[o]) * s + beta[o];
        }
    }

    for (int kt = 0; kt < 512; kt += 64) {
#pragma unroll
        for (int s = 0; s < 2; ++s) {
            int q = tid + 256 * s;
            int r = q >> 3, c = (q & 7) * 8;
            *(short8*)&Ald[r][c] = *(const short8*)(Wvb + (size_t)(m0g + r) * 512 + kt + c);
            *(short8*)&Bld[r][c] = *(const short8*)(catb + (size_t)(n0g + r) * 512 + kt + c);
        }
        __syncthreads();
#pragma unroll
        for (int ks = 0; ks < 2; ++ks) {
            short8 a[2], b[2];
#pragma unroll
            for (int i = 0; i < 2; ++i) a[i] = *(const short8*)&Ald[wm * 32 + i * 16 + l15][ks * 32 + lk];
#pragma unroll
            for (int j = 0; j < 2; ++j) b[j] = *(const short8*)&Bld[wn * 32 + j * 16 + l15][ks * 32 + lk];
#pragma unroll
            for (int i = 0; i < 2; ++i)
#pragma unroll
                for (int j = 0; j < 2; ++j) acc[i][j] = mfma16(a[i], b[j], acc[i][j]);
        }
        __syncthreads();
    }
#pragma unroll
    for (int i = 0; i < 2; ++i) {
        int ob = m0g + wm * 32 + i * 16 + (lane >> 4) * 4;
#pragma unroll
        for (int j = 0; j < 2; ++j) {
            int px = n0g + wn * 32 + j * 16 + l15;
            int b = px / HW, p = px - b * HW;
            f32x4 v = acc[i][j];
#pragma unroll
            for (int r = 0; r < 4; ++r) {
                out[((size_t)(b * 256 + ob + r)) * HW + p] = fmaxf(v[r] * sc_[i][r] + sh_[i][r], 0.f);
            }
        }
    }
}

extern "C" void kernel_launch(void* const* d_in, const int* in_sizes, int n_in,
                              void* d_out, int out_size, void* d_ws, size_t ws_size,
                              hipStream_t stream) {
    const float* x     = (const float*)d_in[0];
    const float* Wq    = (const float*)d_in[1];
    const float* Wk    = (const float*)d_in[2];
    const float* Wv    = (const float*)d_in[3];
    const float* bv    = (const float*)d_in[4];
    const float* gamma = (const float*)d_in[5];
    const float* beta  = (const float*)d_in[6];
    const float* rmean = (const float*)d_in[7];
    const float* rvar  = (const float*)d_in[8];
    float* out = (float*)d_out;

    float* Qall = (float*)d_ws;                              // [4*HW][64] f32
    float* Qn   = Qall + (size_t)4 * HW * 64;                // [2*HW][64] f32
    unsigned short* Kb = (unsigned short*)(Qn + (size_t)2 * HW * 64);  // [6*HW][64] bf16
    unsigned short* catb   = Kb + (size_t)6 * HW * 64;       // [4*HW][512]
    unsigned short* xlo    = catb + (size_t)4 * HW * 512;    // [4*HW][256]
    unsigned short* xt1lo  = xlo + (size_t)4 * HW * 256;     // [2*HW][256]
    unsigned short* Wqk_hi = xt1lo + (size_t)2 * HW * 256;   // [128][256]
    unsigned short* Wqk_lo = Wqk_hi + 128 * 256;
    unsigned short* Wvb    = Wqk_lo + 128 * 256;             // [256][512]

    prep<<<3648, 256, 0, stream>>>(x, Wq, Wk, Wv, catb, xlo, Wqk_hi, Wqk_lo, Wvb);

    // Q (f32) and K (bf16, rows 0..4HW) for all 4 batches
    projqk<<<dim3(392, 2), 256, 0, stream>>>(Wqk_hi, Wqk_lo, catb, 512, xlo, Qall, Kb);

    // align 1: ta = x[2:4], tb = x[0:2] -> xt1 (hi -> catb cols 256.., lo -> xt1lo)
    attn_kernel<<<1568, 256, 0, stream>>>(Qall + (size_t)2 * HW * 64, Kb,
                                          /*selfOff=*/2 * HW, /*kbOff=*/0,
                                          catb, catb + 256, xt1lo);

    // Q,K of xt1 (K -> Kb rows 4HW..6HW)
    projqk<<<dim3(196, 2), 256, 0, stream>>>(Wqk_hi, Wqk_lo, catb + 256, 512, xt1lo,
                                             Qn, Kb + (size_t)4 * HW * 64);

    // align 2: ta = xt1, tb = x[2:4] -> xt2
    attn_kernel<<<1568, 256, 0, stream>>>(Qn, Kb,
                                          /*selfOff=*/4 * HW, /*kbOff=*/2 * HW,
                                          catb + (size_t)2 * HW * 512,
                                          catb + (size_t)2 * HW * 512 + 256, nullptr);

    // fused 1x1 conv (512->256) + BN + ReLU
    conv_mfma<<<dim3(196, 4), 256, 0, stream>>>(catb, Wvb, bv, gamma, beta, rmean, rvar, out);
}